// Round 3
// baseline (23.290 us; speedup 1.0000x reference)
//
#include <hip/hip_runtime.h>
#include <math.h>

#define NPTS    30000
#define NB      16
#define CNT_W   65
#define CNT_SZ  (65 * 65)     // 4225
#define NIMG    64            // 2 rot * 2 clouds * 16 batches
#define NSPLIT  4
#define GPS     (NPTS / 4 / NSPLIT)   // 1875 four-point groups per split

__device__ inline void eul2rot(const float* t, float R[9]) {
    float s0 = sinf(t[0]), s1 = sinf(t[1]), s2 = sinf(t[2]);
    float c0 = cosf(t[0]), c1 = cosf(t[1]), c2 = cosf(t[2]);
    R[0] = c1 * c2; R[1] = s0 * s1 * c2 - s2 * c0; R[2] = s1 * c0 * c2 + s0 * s2;
    R[3] = s2 * c1; R[4] = s0 * s1 * s2 + c0 * c2; R[5] = s1 * s2 * c0 - s0 * c2;
    R[6] = -s1;     R[7] = s0 * c1;                R[8] = c0 * c1;
}

__device__ inline void splat1(float x, float y, float zz, const float R[9],
                              unsigned* lcnt) {
    float cx = R[0] * x + R[1] * y + R[2] * zz;
    float cy = R[3] * x + R[4] * y + R[5] * zz;
    float cz = R[6] * x + R[7] * y + R[8] * zz;
    float inv = __builtin_amdgcn_rcpf(cz + 2.5f);   // shared 1/z for u and v
    float u = fmaf(120.0f * cx, inv, 36.0f);
    float v = fmaf(120.0f * cy, inv, 36.0f);
    int x4 = (int)rintf(u);   // round-half-even, matches jnp.round
    int y4 = (int)rintf(v);
    if (x4 >= 0 && x4 <= 64 && y4 >= 0 && y4 <= 64)
        atomicAdd(&lcnt[x4 * CNT_W + y4], 1u);
}

// ------------- histogram: read points ONCE, splat for BOTH rotations -------------
// grid: 2 clouds * 16 batches * NSPLIT = 128 blocks, 512 threads
__global__ __launch_bounds__(512) void hist_kernel(const float* __restrict__ pc1,
                                                   const float* __restrict__ pc2,
                                                   const float* __restrict__ rot,
                                                   unsigned* __restrict__ pcnts,
                                                   float* __restrict__ out) {
    __shared__ unsigned lc0[CNT_SZ];   // rotation 0
    __shared__ unsigned lc1[CNT_SZ];   // rotation 1
    int bid   = blockIdx.x;
    int split = bid & (NSPLIT - 1);
    int cb    = bid >> 2;             // c*16 + b
    int b = cb & 15;
    int c = cb >> 4;
    int tid = threadIdx.x;

    if (bid == 0 && tid == 0) out[0] = 0.0f;   // stream-ordered before convbce

    for (int i = tid; i < CNT_SZ; i += 512) { lc0[i] = 0u; lc1[i] = 0u; }

    float R0[9], R1[9];
    eul2rot(rot, R0);
    eul2rot(rot + 3, R1);
    const float* pc = (c ? pc2 : pc1) + (size_t)b * NPTS * 3;
    const float4* pc4 = (const float4*)pc;
    __syncthreads();

    // each group g covers points 4g..4g+3 (48 contiguous bytes = 3 float4)
    int gend = (split + 1) * GPS;
    for (int g = split * GPS + tid; g < gend; g += 512) {
        float4 a  = pc4[3 * g + 0];
        float4 bq = pc4[3 * g + 1];
        float4 cq = pc4[3 * g + 2];
        splat1(a.x, a.y, a.z, R0, lc0);   splat1(a.x, a.y, a.z, R1, lc1);
        splat1(a.w, bq.x, bq.y, R0, lc0); splat1(a.w, bq.x, bq.y, R1, lc1);
        splat1(bq.z, bq.w, cq.x, R0, lc0);splat1(bq.z, bq.w, cq.x, R1, lc1);
        splat1(cq.y, cq.z, cq.w, R0, lc0);splat1(cq.y, cq.z, cq.w, R1, lc1);
    }
    __syncthreads();

    // imgi = r*32 + c*16 + b ; partial slot = imgi*NSPLIT + split
    unsigned* g0 = pcnts + (size_t)((c * 16 + b) * NSPLIT + split) * CNT_SZ;
    unsigned* g1 = pcnts + (size_t)((32 + c * 16 + b) * NSPLIT + split) * CNT_SZ;
    for (int i = tid; i < CNT_SZ; i += 512) { g0[i] = lc0[i]; g1[i] = lc1[i]; }
}

// ---------------- fused conv(5x5) + per-image max + BCE ----------------
// grid: 32 blocks (one per (r,b) pair), 1024 threads
__global__ __launch_bounds__(1024) void convbce_kernel(const unsigned* __restrict__ pcnts,
                                                       float* __restrict__ out) {
    __shared__ float lcA[CNT_SZ];
    __shared__ float lcB[CNT_SZ];
    __shared__ float redA[16], redB[16], redS[16];
    int bid = blockIdx.x;        // r*16 + b
    int b = bid & 15, r = bid >> 4;
    int i1 = r * 32 + b;          // pc1 image
    int i2 = r * 32 + 16 + b;     // pc2 image
    int tid = threadIdx.x;

    const unsigned* pa = pcnts + (size_t)i1 * NSPLIT * CNT_SZ;
    const unsigned* pb = pcnts + (size_t)i2 * NSPLIT * CNT_SZ;
    for (int i = tid; i < CNT_SZ; i += 1024) {
        lcA[i] = (float)(pa[i] + pa[i + CNT_SZ] + pa[i + 2 * CNT_SZ] + pa[i + 3 * CNT_SZ]);
        lcB[i] = (float)(pb[i] + pb[i + CNT_SZ] + pb[i + 2 * CNT_SZ] + pb[i + 3 * CNT_SZ]);
    }

    // GK[i][j] = exp(-sqrt((i-5)^2+(j-5)^2)/0.4), i,j in 0..4
    float GK[25];
#pragma unroll
    for (int i = 0; i < 5; i++)
#pragma unroll
        for (int j = 0; j < 5; j++) {
            float d = sqrtf((float)((i - 5) * (i - 5) + (j - 5) * (j - 5)));
            GK[i * 5 + j] = expf(-d / 0.4f);
        }
    __syncthreads();

    // conv: 4 outputs per image per thread, held in registers
    float cA[4], cB[4];
    float mA = 0.0f, mB = 0.0f;
#pragma unroll
    for (int k = 0; k < 4; k++) {
        int o = tid + k * 1024;
        int px = o >> 6, py = o & 63;
        float sA = 0.0f, sB = 0.0f;
#pragma unroll
        for (int i = 0; i < 5; i++) {
            int x = px + 2 + i;
            if (x > 64) continue;
            const float* rowA = &lcA[x * CNT_W];
            const float* rowB = &lcB[x * CNT_W];
#pragma unroll
            for (int j = 0; j < 5; j++) {
                int y = py + 2 + j;
                if (y > 64) continue;
                float w = GK[i * 5 + j];
                sA += w * rowA[y];
                sB += w * rowB[y];
            }
        }
        cA[k] = sA; cB[k] = sB;
        mA = fmaxf(mA, sA); mB = fmaxf(mB, sB);
    }

    // block max reduce (16 waves)
#pragma unroll
    for (int off = 32; off > 0; off >>= 1) {
        mA = fmaxf(mA, __shfl_down(mA, off));
        mB = fmaxf(mB, __shfl_down(mB, off));
    }
    int wave = tid >> 6;
    if ((tid & 63) == 0) { redA[wave] = mA; redB[wave] = mB; }
    __syncthreads();
    float maxA = redA[0], maxB = redB[0];
#pragma unroll
    for (int w = 1; w < 16; w++) {
        maxA = fmaxf(maxA, redA[w]);
        maxB = fmaxf(maxB, redB[w]);
    }

    float invA = 1.0f / maxA, invB = 1.0f / maxB;
    float s = 0.0f;
#pragma unroll
    for (int k = 0; k < 4; k++) {
        float e1 = cA[k] * invA;
        float e2 = cB[k] * invB;
        float lp = fmaxf(logf(e1), -100.0f);
        float lq = fmaxf(logf(1.0f - e1), -100.0f);
        s += e2 * lp + (1.0f - e2) * lq;
    }
#pragma unroll
    for (int off = 32; off > 0; off >>= 1) s += __shfl_down(s, off);
    if ((tid & 63) == 0) redS[wave] = s;
    __syncthreads();
    if (tid == 0) {
        float tot = 0.0f;
#pragma unroll
        for (int w = 0; w < 16; w++) tot += redS[w];
        atomicAdd(out, -tot);
    }
}

extern "C" void kernel_launch(void* const* d_in, const int* in_sizes, int n_in,
                              void* d_out, int out_size, void* d_ws, size_t ws_size,
                              hipStream_t stream) {
    const float* pc1 = (const float*)d_in[0];
    const float* pc2 = (const float*)d_in[1];
    const float* rot = (const float*)d_in[2];
    float* out = (float*)d_out;

    unsigned* pcnts = (unsigned*)d_ws;   // NIMG*NSPLIT * 4225 u32 = 4.3 MB

    hist_kernel<<<2 * NB * NSPLIT, 512, 0, stream>>>(pc1, pc2, rot, pcnts, out);
    convbce_kernel<<<32, 1024, 0, stream>>>(pcnts, out);
}